// Round 1
// baseline (9.706 us; speedup 1.0000x reference)
//
#include <hip/hip_runtime.h>
#include <math.h>

// out[t] = sum_{d} x[t-d] * w(d),  w(d) = exp(-((d-0.5)-mu)^2/(2s^2)) / (s*sqrt(2pi))
// d in [-8191, 8191] (kernel support), j = t-d in [0, T-1] (zero pad).
// Gaussian taps with |d-0.5-mu| > ~13.2*sigma underflow to 0 in f32 ->
// truncate at R = 13.5*|s| + |mu| + 2 (device-computed, deterministic in inputs).
__global__ void gauss_conv1d(const float* __restrict__ x,
                             const float* __restrict__ sigma,
                             const float* __restrict__ mu,
                             float* __restrict__ out,
                             int T) {
    int t = blockIdx.x * blockDim.x + threadIdx.x;
    if (t >= T) return;

    float s = sigma[0];
    float m = mu[0];
    float inv2s2 = 1.0f / (2.0f * s * s);
    float norm   = 1.0f / (s * sqrtf(6.283185307179586f));

    // truncation radius: beyond |u| > 13.2*s, exp(-u^2/(2 s^2)) < FLT_MIN (contributes 0)
    float rf = 13.5f * fabsf(s) + fabsf(m) + 2.0f;
    int R = (rf >= 8191.0f) ? 8191 : ((int)rf + 1);

    int dhi = R;            // j = t - d >= 0     -> d <= t
    int dlo = -R;           // j = t - d <= T-1   -> d >= t - (T-1)
    if (dhi > t) dhi = t;
    if (dlo < t - (T - 1)) dlo = t - (T - 1);

    float acc = 0.0f;
    for (int d = dlo; d <= dhi; ++d) {
        float u = ((float)d - 0.5f) - m;
        acc = fmaf(x[t - d], __expf(-u * u * inv2s2), acc);
    }
    out[t] = acc * norm;
}

extern "C" void kernel_launch(void* const* d_in, const int* in_sizes, int n_in,
                              void* d_out, int out_size, void* d_ws, size_t ws_size,
                              hipStream_t stream) {
    const float* x     = (const float*)d_in[0];
    const float* sigma = (const float*)d_in[1];
    const float* mu    = (const float*)d_in[2];
    float* out = (float*)d_out;
    int T = in_sizes[0];

    const int block = 256;
    const int grid  = (T + block - 1) / block;
    gauss_conv1d<<<grid, block, 0, stream>>>(x, sigma, mu, out, T);
}